// Round 4
// baseline (313.184 us; speedup 1.0000x reference)
//
#include <hip/hip_runtime.h>
#include <math.h>

#define A_DIM 128   // image height/width
#define N_G   64    // glimpse size
#define HD    512   // h_dim

typedef short short8 __attribute__((ext_vector_type(8)));   // 8 bf16 = 4 VGPRs (MFMA A/B frag)
typedef float floatx4 __attribute__((ext_vector_type(4)));  // MFMA C/D frag

static __device__ __forceinline__ unsigned short f2bf(float f) {
  union { float f; unsigned u; } v; v.f = f;
  unsigned r = (v.u + 0x7fffu + ((v.u >> 16) & 1u)) >> 16;   // RNE
  return (unsigned short)r;
}

static __device__ __forceinline__ short8 pack8(float4 a, float4 b) {
  short8 r;
  r[0] = (short)f2bf(a.x); r[1] = (short)f2bf(a.y);
  r[2] = (short)f2bf(a.z); r[3] = (short)f2bf(a.w);
  r[4] = (short)f2bf(b.x); r[5] = (short)f2bf(b.y);
  r[6] = (short)f2bf(b.z); r[7] = (short)f2bf(b.w);
  return r;
}

// Builds pre-swizzled MFMA fragment tables in d_ws:
//  FXfrag[tile][kk][lane][j] = FX[m = tile*16 + (lane&15)][c = kk*32 + (lane>>4)*8 + j] / sumX
//  FYfrag[tile][kk][lane][j] = gamma * FY[n = ...][a = ...] / sumY
__global__ __launch_bounds__(512) void fb_setup_kernel(
    const float* __restrict__ h, const float* __restrict__ Ww,
    const float* __restrict__ Wb, unsigned short* __restrict__ FXfrag,
    unsigned short* __restrict__ FYfrag) {
  __shared__ float p[5];
  __shared__ float redX[8], redY[8];
  __shared__ float invs[2];
  const int tid = threadIdx.x, wave = tid >> 6, lane = tid & 63;

  if (wave < 5) {
    float s = 0.f;
    for (int k = lane; k < HD; k += 64) s += h[k] * Ww[wave * HD + k];
#pragma unroll
    for (int off = 32; off > 0; off >>= 1) s += __shfl_down(s, off);
    if (lane == 0) p[wave] = s + Wb[wave];
  }
  __syncthreads();

  const float gX = 64.5f * (p[0] + 1.0f);
  const float gY = 64.5f * (p[1] + 1.0f);
  const float var = expf(p[2] + 1e-8f);
  const float dd = expf(p[3]) * (127.0f / 63.0f);
  const float gamma = expf(p[4]);
  const float two_var = 2.0f * var;

  float sX = 0.f, sY = 0.f;
  for (int i = tid; i < N_G * A_DIM; i += 512) {
    const int n = i >> 7, a = i & 127;
    const float off_n = ((float)n - 32.5f) * dd;
    const float tx = (float)a - (gX + off_n);
    const float ty = (float)a - (gY + off_n);
    sX += expf(-(tx * tx) / two_var);
    sY += expf(-(ty * ty) / two_var);
  }
#pragma unroll
  for (int off = 32; off > 0; off >>= 1) {
    sX += __shfl_down(sX, off);
    sY += __shfl_down(sY, off);
  }
  if (lane == 0) { redX[wave] = sX; redY[wave] = sY; }
  __syncthreads();
  if (tid == 0) {
    float tX = 0.f, tY = 0.f;
#pragma unroll
    for (int w = 0; w < 8; ++w) { tX += redX[w]; tY += redY[w]; }
    invs[0] = 1.0f / tX;
    invs[1] = gamma / tY;
  }
  __syncthreads();
  const float isX = invs[0], isYg = invs[1];

  // 8192 fragment elements per table: i = tile*2048 + kk*512 + lane*8 + j
  for (int i = tid; i < 4 * 4 * 64 * 8; i += 512) {
    const int j = i & 7;
    const int ln = (i >> 3) & 63;
    const int kk = (i >> 9) & 3;
    const int tl = (i >> 11) & 3;
    const int mn = tl * 16 + (ln & 15);
    const int ca = kk * 32 + ((ln >> 4) << 3) + j;
    const float off_mn = ((float)mn - 32.5f) * dd;
    const float tx = (float)ca - (gX + off_mn);
    const float ty = (float)ca - (gY + off_mn);
    FXfrag[i] = f2bf(expf(-(tx * tx) / two_var) * isX);
    FYfrag[i] = f2bf(expf(-(ty * ty) / two_var) * isYg);
  }
}

// One block (256 thr, 4 waves) per (batch, tensor) image.
// Phase A: U[a][m] = sum_c x[a][c] * FX[m][c]   (A-frags straight from global fp32,
//          all 16 float4 loads issued up-front for full MLP)
//          -> U^T[m][a] bf16 in LDS, XOR chunk-swizzled
// Phase B: out[n][m] = sum_a FY[n][a] * U[a][m]  (FY frags prefetched pre-barrier)
__global__ __launch_bounds__(256, 3) void glimpse_kernel(
    const float* __restrict__ x, const float* __restrict__ xh,
    const unsigned short* __restrict__ FXfrag,
    const unsigned short* __restrict__ FYfrag,
    float* __restrict__ out) {
  const int img = blockIdx.x;
  const int b = img >> 1, t = img & 1;
  const float* __restrict__ src = (t ? xh : x) + (size_t)b * (A_DIM * A_DIM);
  float* __restrict__ dst = out + (size_t)b * (2 * N_G * N_G) + t * (N_G * N_G);

  __shared__ __align__(16) unsigned short us[N_G * A_DIM];  // U^T[m][a], swizzled

  const int tid = threadIdx.x;
  const int w = tid >> 6, lane = tid & 63;
  const int quad = lane >> 4, lm = lane & 15;

  // ---- phase A ----
  short8 aF2[4];  // phase-B FY fragments, prefetched early (independent of phase A)
  {
    const float4* __restrict__ src4 = (const float4*)src;

    // 1) issue ALL x loads back-to-back (16 float4 = 256 B/thread in flight)
    float4 u[16];
#pragma unroll
    for (int i = 0; i < 2; ++i)
#pragma unroll
      for (int kk = 0; kk < 4; ++kk) {
        const int idx = ((2 * w + i) * 16 + lm) * 32 + kk * 8 + quad * 2;
        u[(i * 4 + kk) * 2]     = src4[idx];
        u[(i * 4 + kk) * 2 + 1] = src4[idx + 1];
      }

    // 2) prefetch phase-B A-operands (L2-hot, shared by all blocks)
#pragma unroll
    for (int kk = 0; kk < 4; ++kk)
      aF2[kk] = *(const short8*)(FYfrag + ((size_t)(w * 4 + kk) * 64 + lane) * 8);

    // 3) pack to bf16 fragments
    short8 aF[2][4];
#pragma unroll
    for (int i = 0; i < 2; ++i)
#pragma unroll
      for (int kk = 0; kk < 4; ++kk)
        aF[i][kk] = pack8(u[(i * 4 + kk) * 2], u[(i * 4 + kk) * 2 + 1]);

    floatx4 acc[2][4];
#pragma unroll
    for (int i = 0; i < 2; ++i)
#pragma unroll
      for (int j = 0; j < 4; ++j) acc[i][j] = (floatx4)0.f;

#pragma unroll
    for (int kk = 0; kk < 4; ++kk) {
      short8 bF[4];
#pragma unroll
      for (int j = 0; j < 4; ++j)
        bF[j] = *(const short8*)(FXfrag + ((size_t)(j * 4 + kk) * 64 + lane) * 8);
#pragma unroll
      for (int i = 0; i < 2; ++i)
#pragma unroll
        for (int j = 0; j < 4; ++j)
          acc[i][j] = __builtin_amdgcn_mfma_f32_16x16x32_bf16(aF[i][kk], bF[j], acc[i][j], 0, 0, 0);
    }

    // write U^T: lane holds (a = (2w+i)*16 + quad*4 + r, m = j*16 + lm)
#pragma unroll
    for (int i = 0; i < 2; ++i) {
      const int ch = (2 * w + i) * 2 + (quad >> 1);   // 16-B chunk index along a
      const int half = (quad & 1) * 4;                // 8-B half within chunk
#pragma unroll
      for (int j = 0; j < 4; ++j) {
        uint2 pk;
        pk.x = (unsigned)f2bf(acc[i][j][0]) | ((unsigned)f2bf(acc[i][j][1]) << 16);
        pk.y = (unsigned)f2bf(acc[i][j][2]) | ((unsigned)f2bf(acc[i][j][3]) << 16);
        *(uint2*)&us[(j * 16 + lm) * A_DIM + ((ch ^ lm) << 3) + half] = pk;
      }
    }
  }
  __syncthreads();

  // ---- phase B: wave w owns n-tile w, all 4 m-tiles ----
  {
    floatx4 acc2[4];
#pragma unroll
    for (int j = 0; j < 4; ++j) acc2[j] = (floatx4)0.f;

#pragma unroll
    for (int kk = 0; kk < 4; ++kk) {
#pragma unroll
      for (int mt = 0; mt < 4; ++mt) {
        const int ch = (kk * 4 + quad) ^ lm;          // swizzled chunk position
        const short8 bF = *(const short8*)&us[(mt * 16 + lm) * A_DIM + (ch << 3)];
        acc2[mt] = __builtin_amdgcn_mfma_f32_16x16x32_bf16(aF2[kk], bF, acc2[mt], 0, 0, 0);
      }
    }

#pragma unroll
    for (int mt = 0; mt < 4; ++mt)
#pragma unroll
      for (int r = 0; r < 4; ++r)
        dst[(w * 16 + quad * 4 + r) * N_G + mt * 16 + lm] = acc2[mt][r];
  }
}

extern "C" void kernel_launch(void* const* d_in, const int* in_sizes, int n_in,
                              void* d_out, int out_size, void* d_ws, size_t ws_size,
                              hipStream_t stream) {
  const float* x  = (const float*)d_in[0];   // (2048, 16384)
  const float* xh = (const float*)d_in[1];   // (2048, 16384)
  const float* h  = (const float*)d_in[2];   // (2048, 512) -- only row 0 used
  const float* Ww = (const float*)d_in[3];   // (5, 512)
  const float* Wb = (const float*)d_in[4];   // (5,)
  float* out = (float*)d_out;                // (2048, 8192)

  unsigned short* FXfrag = (unsigned short*)d_ws;        // 8192 bf16 = 16 KB
  unsigned short* FYfrag = FXfrag + 4 * 4 * 64 * 8;      // 8192 bf16 = 16 KB

  fb_setup_kernel<<<1, 512, 0, stream>>>(h, Ww, Wb, FXfrag, FYfrag);
  glimpse_kernel<<<4096, 256, 0, stream>>>(x, xh, FXfrag, FYfrag, out);
}